// Round 7
// baseline (222.115 us; speedup 1.0000x reference)
//
#include <hip/hip_runtime.h>

#define Lc 1024
#define Dc 512
#define Hc 8
#define DHc 64

typedef __attribute__((ext_vector_type(8))) short bf16x8;
typedef __attribute__((ext_vector_type(4))) float f32x4;

typedef __attribute__((address_space(1))) const unsigned int guint;
typedef __attribute__((address_space(3))) unsigned int luint;

__device__ __forceinline__ void gload_lds16(const void* g, void* l) {
    __builtin_amdgcn_global_load_lds((guint*)g, (luint*)l, 16, 0, 0);
}

__device__ __forceinline__ unsigned short f2bf(float f) {
    unsigned u = __float_as_uint(f);
    u += 0x7fffu + ((u >> 16) & 1u);          // round-to-nearest-even
    return (unsigned short)(u >> 16);
}
__device__ __forceinline__ unsigned short f2bft(float f) {   // truncate
    return (unsigned short)(__float_as_uint(f) >> 16);
}
__device__ __forceinline__ unsigned pk2(float a, float b) {
    return (unsigned)f2bf(a) | ((unsigned)f2bf(b) << 16);
}
__device__ __forceinline__ float bf2f(unsigned short s) { return __uint_as_float(((unsigned)s) << 16); }

// ---------------------------------------------------------------------------
// fp32 -> bf16 cast of weights only: Wq, Wk, Wv, Wo, We
// ---------------------------------------------------------------------------
__global__ void cvt_w_kernel(
    const float* __restrict__ Wq, const float* __restrict__ Wk,
    const float* __restrict__ Wv, const float* __restrict__ Wo,
    const float* __restrict__ We,
    unsigned short* __restrict__ wqb, unsigned short* __restrict__ wkb,
    unsigned short* __restrict__ wvb, unsigned short* __restrict__ wob,
    unsigned short* __restrict__ wet)
{
    int bid = blockIdx.x;
    const float* src; unsigned short* dst; size_t base;
    if      (bid < 256)  { src = Wq; dst = wqb; base = (size_t)bid * 1024; }
    else if (bid < 512)  { src = Wk; dst = wkb; base = (size_t)(bid-256) * 1024; }
    else if (bid < 768)  { src = Wv; dst = wvb; base = (size_t)(bid-512) * 1024; }
    else if (bid < 1024) { src = Wo; dst = wob; base = (size_t)(bid-768) * 1024; }
    else                 { src = We; dst = wet; base = (size_t)(bid-1024) * 1024; }
    size_t i = base + (size_t)threadIdx.x * 4;
    float4 a = *(const float4*)&src[i];
    *(uint2*)&dst[i] = make_uint2(pk2(a.x, a.y), pk2(a.z, a.w));
}

// ---------------------------------------------------------------------------
// QKV projection, bf16 MFMA, BK=64. A staged from fp32 x (VGPR cvt route),
// B (bf16 weights) via DMA. qscale = 0.125*log2(e) folded into Q.
// z<2 (q,k): operand-swapped MFMA -> f32x4 spans 4 consecutive dh -> uint2
//            stores to (B,H,L,DH).
// z==2 (v):  normal orientation + LDS-transpose epilogue -> V^T (B,H,DH,L).
// ---------------------------------------------------------------------------
__global__ __launch_bounds__(256, 3) void proj_mfma_kernel(
    const float* __restrict__ x,
    const unsigned short* __restrict__ wq, const unsigned short* __restrict__ wk,
    const unsigned short* __restrict__ wv,
    unsigned short* __restrict__ qo, unsigned short* __restrict__ ko,
    unsigned short* __restrict__ vtg, float qscale)
{
    const unsigned short* W;
    if (blockIdx.z == 0)      W = wq;
    else if (blockIdx.z == 1) W = wk;
    else                      W = wv;

    __shared__ unsigned short smem[128 * 136];      // As(8192) Bs(8192) / Ts(17408)
    unsigned short* As = smem;
    unsigned short* Bs = smem + 8192;

    const int t = threadIdx.x;
    const int lane = t & 63, w = t >> 6;
    const int lq = lane >> 4, ln = lane & 15;
    const int m0 = blockIdx.y * 128, n0 = blockIdx.x * 128;
    const int wm = (w & 1) * 64, wn = (w >> 1) * 64;
    const int srow = t >> 3;                        // 0..31   (B-DMA row)
    const int lsg  = ((t & 7) ^ ((t >> 3) & 7)) * 8;  // B-DMA swizzled src seg
    const int arow = t >> 1, ahalf = (t & 1) * 4;   // A-stage row / seg half
    const int key  = ln & 7;

    f32x4 acc[4][4];
    #pragma unroll
    for (int i = 0; i < 4; i++)
        #pragma unroll
        for (int j = 0; j < 4; j++) acc[i][j] = (f32x4){0.f,0.f,0.f,0.f};

    for (int c0 = 0; c0 < 512; c0 += 64) {
        __syncthreads();
        // ---- B via DMA (swizzled)
        #pragma unroll
        for (int g = 0; g < 4; g++)
            gload_lds16(&W[(size_t)(n0 + 32*g + srow) * 512 + c0 + lsg], &Bs[(32*g + srow)*64 + (t&7)*8]);
        // ---- A from fp32 x, cvt in VGPR, swizzled b128 writes
        #pragma unroll
        for (int g = 0; g < 4; g++) {
            int sl   = ahalf + g;                   // logical seg
            int pseg = sl ^ (arow & 7);             // physical seg
            const float* s = &x[(size_t)(m0 + arow) * 512 + c0 + sl*8];
            float4 a = *(const float4*)&s[0];
            float4 b = *(const float4*)&s[4];
            uint4 pv = make_uint4(pk2(a.x,a.y), pk2(a.z,a.w), pk2(b.x,b.y), pk2(b.z,b.w));
            *(uint4*)&As[arow*64 + pseg*8] = pv;
        }
        __syncthreads();

        #pragma unroll
        for (int kk = 0; kk < 2; kk++) {
            bf16x8 af[4], bf[4];
            #pragma unroll
            for (int i = 0; i < 4; i++)
                af[i] = *(bf16x8*)&As[(wm + 16*i + ln)*64 + ((kk*4 + lq) ^ key)*8];
            #pragma unroll
            for (int j = 0; j < 4; j++)
                bf[j] = *(bf16x8*)&Bs[(wn + 16*j + ln)*64 + ((kk*4 + lq) ^ key)*8];
            if (blockIdx.z < 2) {
                #pragma unroll
                for (int i = 0; i < 4; i++)
                    #pragma unroll
                    for (int j = 0; j < 4; j++)
                        acc[i][j] = __builtin_amdgcn_mfma_f32_16x16x32_bf16(bf[j], af[i], acc[i][j], 0, 0, 0);
            } else {
                #pragma unroll
                for (int i = 0; i < 4; i++)
                    #pragma unroll
                    for (int j = 0; j < 4; j++)
                        acc[i][j] = __builtin_amdgcn_mfma_f32_16x16x32_bf16(af[i], bf[j], acc[i][j], 0, 0, 0);
            }
        }
    }

    if (blockIdx.z < 2) {
        // swapped: D row-dim = n (W rows), col-dim = m (x rows)
        unsigned short* out = (blockIdx.z == 0) ? qo : ko;
        const float osc = (blockIdx.z == 0) ? qscale : 1.0f;
        #pragma unroll
        for (int i = 0; i < 4; i++) {
            int m = m0 + wm + 16*i + ln;
            int b = m >> 10, l = m & 1023;
            #pragma unroll
            for (int j = 0; j < 4; j++) {
                int nb = n0 + wn + 16*j + 4*lq;     // 4-aligned dh base
                int h = nb >> 6, dh = nb & 63;
                *(uint2*)&out[((size_t)((b*Hc + h)*Lc + l))*DHc + dh] =
                    make_uint2(pk2(acc[i][j][0]*osc, acc[i][j][1]*osc),
                               pk2(acc[i][j][2]*osc, acc[i][j][3]*osc));
            }
        }
    } else {
        // V: transpose through LDS, write V^T (B,H,DH,L)
        __syncthreads();
        unsigned short* Ts = smem;      // [n_local][m_local] stride 136
        #pragma unroll
        for (int i = 0; i < 4; i++) {
            int mlb = wm + 16*i + 4*lq;
            #pragma unroll
            for (int j = 0; j < 4; j++) {
                int nl = wn + 16*j + ln;
                *(uint2*)&Ts[nl*136 + mlb] = make_uint2(pk2(acc[i][j][0], acc[i][j][1]),
                                                        pk2(acc[i][j][2], acc[i][j][3]));
            }
        }
        __syncthreads();
        const int b = m0 >> 10, l0m = m0 & 1023;
        const int nl = t >> 1, seg = (t & 1) * 64;
        const int ng = n0 + nl, h = ng >> 6, dh = ng & 63;
        unsigned short* dst = vtg + (((size_t)(b*Hc + h))*DHc + dh)*Lc + l0m + seg;
        #pragma unroll
        for (int u = 0; u < 8; u++)
            *(uint4*)&dst[8*u] = *(uint4*)&Ts[nl*136 + seg + 8*u];
    }
}

// ---------------------------------------------------------------------------
// Output GEMM, bf16 MFMA, BK=64, swizzled: out = awb @ Wo^T + bo (fp32 out)
// ---------------------------------------------------------------------------
__global__ __launch_bounds__(256, 3) void out_mfma_kernel(
    const unsigned short* __restrict__ A, const unsigned short* __restrict__ W,
    const float* __restrict__ bias, float* __restrict__ out)
{
    __shared__ unsigned short As[128 * 64];
    __shared__ unsigned short Bs[128 * 64];

    const int t = threadIdx.x;
    const int lane = t & 63, w = t >> 6;
    const int lq = lane >> 4, ln = lane & 15;
    const int m0 = blockIdx.y * 128, n0 = blockIdx.x * 128;
    const int wm = (w & 1) * 64, wn = (w >> 1) * 64;
    const int srow = t >> 3;
    const int lsg  = ((t & 7) ^ ((t >> 3) & 7)) * 8;
    const int key  = ln & 7;

    f32x4 acc[4][4];
    #pragma unroll
    for (int i = 0; i < 4; i++)
        #pragma unroll
        for (int j = 0; j < 4; j++) acc[i][j] = (f32x4){0.f,0.f,0.f,0.f};

    for (int c0 = 0; c0 < 512; c0 += 64) {
        __syncthreads();
        #pragma unroll
        for (int g = 0; g < 4; g++) {
            gload_lds16(&A[(size_t)(m0 + 32*g + srow) * 512 + c0 + lsg], &As[(32*g + srow)*64 + (t&7)*8]);
            gload_lds16(&W[(size_t)(n0 + 32*g + srow) * 512 + c0 + lsg], &Bs[(32*g + srow)*64 + (t&7)*8]);
        }
        __syncthreads();

        #pragma unroll
        for (int kk = 0; kk < 2; kk++) {
            bf16x8 af[4], bf[4];
            #pragma unroll
            for (int i = 0; i < 4; i++)
                af[i] = *(bf16x8*)&As[(wm + 16*i + ln)*64 + ((kk*4 + lq) ^ key)*8];
            #pragma unroll
            for (int j = 0; j < 4; j++)
                bf[j] = *(bf16x8*)&Bs[(wn + 16*j + ln)*64 + ((kk*4 + lq) ^ key)*8];
            #pragma unroll
            for (int i = 0; i < 4; i++)
                #pragma unroll
                for (int j = 0; j < 4; j++)
                    acc[i][j] = __builtin_amdgcn_mfma_f32_16x16x32_bf16(af[i], bf[j], acc[i][j], 0, 0, 0);
        }
    }

    float bb[4];
    #pragma unroll
    for (int j = 0; j < 4; j++) bb[j] = bias[n0 + wn + 16*j + ln];

    #pragma unroll
    for (int i = 0; i < 4; i++) {
        #pragma unroll
        for (int r = 0; r < 4; r++) {
            int m = m0 + wm + 16*i + 4*lq + r;
            #pragma unroll
            for (int j = 0; j < 4; j++) {
                int n = n0 + wn + 16*j + ln;
                out[(size_t)m * Dc + n] = acc[i][j][r] + bb[j];
            }
        }
    }
}

// ---------------------------------------------------------------------------
// attn v5: v4 + lsum-via-ones-MFMA + exp2 folding + trunc-P + ring QE addr.
//  - qes ring [e&127][l] stride 70 (odd-bank); panels of 64 e-cols.
//  - row-sums accumulate via MFMA(P, ones) -> no shuffle reductions.
//  - LDS 50.7 KB -> 3 blocks/CU. 2 barriers/iter.
// ---------------------------------------------------------------------------
__global__ __launch_bounds__(256, 3) void attn_v5_kernel(
    const unsigned short* __restrict__ q, const unsigned short* __restrict__ k,
    const unsigned short* __restrict__ vtg, const unsigned short* __restrict__ wet,
    unsigned short* __restrict__ attn)
{
    __shared__ unsigned short ksp [2 * 64 * 32];    // K planes [kk][s][32]
    __shared__ unsigned short vtp [2 * 64 * 32];    // V^T planes [kk][dd][32]
    __shared__ unsigned short wesp[2 * 64 * 32];    // We new-panel planes
    __shared__ unsigned short ps  [2 * 64 * 32];    // P planes (intra-wave)
    __shared__ unsigned short qes [128 * 70];       // QE ring [e&127][l]

    const int t    = threadIdx.x;
    const int lane = t & 63, w = t >> 6;
    const int lq   = lane >> 4, ln = lane & 15;

    // XCD-aware swizzle: consecutive (mod 8) blocks share bh
    const int n   = blockIdx.x;
    const int xcd = n & 7, idx = n >> 3;
    const int bh  = xcd * 8 + (idx >> 4);
    const int l0  = (idx & 15) * 64;

    const unsigned short* qb  = q   + (size_t)bh * (Lc * DHc);
    const unsigned short* kb  = k   + (size_t)bh * (Lc * DHc);
    const unsigned short* vtb = vtg + (size_t)bh * (DHc * Lc);

    const int trow = t >> 2;                            // 0..63
    const int sseg = ((t & 3) ^ ((t >> 4) & 3)) * 8;    // swizzled source seg*8
    const int swz  = (ln >> 2) & 3;                     // frag-read swizzle key

    const bf16x8 onesf = {(short)0x3F80,(short)0x3F80,(short)0x3F80,(short)0x3F80,
                          (short)0x3F80,(short)0x3F80,(short)0x3F80,(short)0x3F80};

    // Q A-frags direct from global (iter-invariant)
    bf16x8 qa[2];
    #pragma unroll
    for (int kk = 0; kk < 2; kk++)
        qa[kk] = *(const bf16x8*)&qb[(size_t)(l0 + 16*w + ln)*64 + kk*32 + lq*8];

    // ---- prologue: stage + compute + scatter panel pb0
    const int pb0 = 15 - (l0 >> 6);
    gload_lds16(&wet[(size_t)(64*pb0 + trow)*64 +      sseg], &wesp[t*8]);
    gload_lds16(&wet[(size_t)(64*pb0 + trow)*64 + 32 + sseg], &wesp[2048 + t*8]);
    __syncthreads();
    {
        f32x4 qec[4];
        #pragma unroll
        for (int c = 0; c < 4; c++) qec[c] = (f32x4){0.f,0.f,0.f,0.f};
        #pragma unroll
        for (int kk = 0; kk < 2; kk++)
            #pragma unroll
            for (int c = 0; c < 4; c++) {
                bf16x8 bf = *(bf16x8*)&wesp[kk*2048 + (16*c + ln)*32 + (lq ^ swz)*8];
                qec[c] = __builtin_amdgcn_mfma_f32_16x16x32_bf16(qa[kk], bf, qec[c], 0, 0, 0);
            }
        const int cb = (pb0 & 1) * 64;
        #pragma unroll
        for (int c = 0; c < 4; c++)
            *(uint2*)&qes[(cb + 16*c + ln)*70 + 16*w + 4*lq] =
                make_uint2(pk2(qec[c][0], qec[c][1]), pk2(qec[c][2], qec[c][3]));
    }

    f32x4 Lacc = (f32x4){0.f, 0.f, 0.f, 0.f};
    f32x4 Ov[4];
    #pragma unroll
    for (int c = 0; c < 4; c++) Ov[c] = (f32x4){0.f, 0.f, 0.f, 0.f};

    int pbOld = pb0 - 1;

    for (int s0 = 0; s0 < Lc; s0 += 64) {
        const int c0  = l0 - s0;
        const int ac0 = c0 < 0 ? -c0 : c0;
        const int pb  = (960 - ac0) >> 6;
        const int newp = (pb > pbOld) ? pb + 1 : pb;
        pbOld = pb;
        const int cb = (newp & 1) * 64;

        __syncthreads();   // (A) prior-iter ksp/vtp/wesp reads complete
        gload_lds16(&kb [(size_t)(s0 + trow)*64 +      sseg], &ksp [t*8]);
        gload_lds16(&kb [(size_t)(s0 + trow)*64 + 32 + sseg], &ksp [2048 + t*8]);
        gload_lds16(&vtb[(size_t)trow*1024 + s0 +      sseg], &vtp [t*8]);
        gload_lds16(&vtb[(size_t)trow*1024 + s0 + 32 + sseg], &vtp [2048 + t*8]);
        gload_lds16(&wet[(size_t)(64*newp + trow)*64 +      sseg], &wesp[t*8]);
        gload_lds16(&wet[(size_t)(64*newp + trow)*64 + 32 + sseg], &wesp[2048 + t*8]);
        __syncthreads();   // (B) staging visible

        // ---- QE new panel (8 MFMAs) + packed transposed scatter
        {
            f32x4 qec[4];
            #pragma unroll
            for (int c = 0; c < 4; c++) qec[c] = (f32x4){0.f,0.f,0.f,0.f};
            #pragma unroll
            for (int kk = 0; kk < 2; kk++)
                #pragma unroll
                for (int c = 0; c < 4; c++) {
                    bf16x8 bf = *(bf16x8*)&wesp[kk*2048 + (16*c + ln)*32 + (lq ^ swz)*8];
                    qec[c] = __builtin_amdgcn_mfma_f32_16x16x32_bf16(qa[kk], bf, qec[c], 0, 0, 0);
                }
            #pragma unroll
            for (int c = 0; c < 4; c++)
                *(uint2*)&qes[(cb + 16*c + ln)*70 + 16*w + 4*lq] =
                    make_uint2(pk2(qec[c][0], qec[c][1]), pk2(qec[c][2], qec[c][3]));
        }

        // ---- S = Q.K^T
        f32x4 sc[4];
        #pragma unroll
        for (int c = 0; c < 4; c++) sc[c] = (f32x4){0.f,0.f,0.f,0.f};
        #pragma unroll
        for (int kk = 0; kk < 2; kk++)
            #pragma unroll
            for (int c = 0; c < 4; c++) {
                bf16x8 bfk = *(bf16x8*)&ksp[kk*2048 + (16*c + ln)*32 + (lq ^ swz)*8];
                sc[c] = __builtin_amdgcn_mfma_f32_16x16x32_bf16(qa[kk], bfk, sc[c], 0, 0, 0);
            }

        // ---- bias gather (ring addr) + exp2 (log2e folded into Q)
        float p[4][4];
        #pragma unroll
        for (int r = 0; r < 4; r++) {
            const int lr = 16*w + 4*lq + r;
            const int dbase = c0 + lr - ln;
            #pragma unroll
            for (int c = 0; c < 4; c++) {
                int d  = dbase - 16*c;
                int ad = d < 0 ? -d : d;
                int m  = 1023 - ad;
                float bias = bf2f(qes[(m & 127)*70 + lr]);
                p[r][c] = __builtin_amdgcn_exp2f(sc[c][r] + bias);
            }
        }

        // ---- P -> ps planes (truncated bf16; intra-wave rows, no barrier)
        #pragma unroll
        for (int r = 0; r < 4; r++) {
            const int lr = 16*w + 4*lq + r;
            #pragma unroll
            for (int c = 0; c < 4; c++) {
                int seg = (((c & 1)*2 + (ln >> 3)) ^ lq);
                ps[(c >> 1)*2048 + lr*32 + seg*8 + (ln & 7)] = f2bft(p[r][c]);
            }
        }

        // ---- O += P @ V ; Lacc += P @ ones (row sums)
        #pragma unroll
        for (int kk = 0; kk < 2; kk++) {
            bf16x8 pa = *(bf16x8*)&ps[kk*2048 + (16*w + ln)*32 + (lq ^ swz)*8];
            Lacc = __builtin_amdgcn_mfma_f32_16x16x32_bf16(pa, onesf, Lacc, 0, 0, 0);
            #pragma unroll
            for (int c = 0; c < 4; c++) {
                bf16x8 vf = *(bf16x8*)&vtp[kk*2048 + (16*c + ln)*32 + (lq ^ swz)*8];
                Ov[c] = __builtin_amdgcn_mfma_f32_16x16x32_bf16(pa, vf, Ov[c], 0, 0, 0);
            }
        }
    }

    // ---- epilogue: normalize, write (B,L,D) bf16
    const int b = bh >> 3, h = bh & 7;
    #pragma unroll
    for (int r = 0; r < 4; r++) {
        float inv = 1.f / Lacc[r];
        int l = l0 + 16*w + 4*lq + r;
        #pragma unroll
        for (int c = 0; c < 4; c++)
            attn[((size_t)(b*Lc + l))*Dc + h*DHc + 16*c + ln] = f2bf(Ov[c][r] * inv);
    }
}

extern "C" void kernel_launch(void* const* d_in, const int* in_sizes, int n_in,
                              void* d_out, int out_size, void* d_ws, size_t ws_size,
                              hipStream_t stream)
{
    (void)in_sizes; (void)n_in; (void)out_size; (void)ws_size;
    const float* x  = (const float*)d_in[0];
    const float* Wq = (const float*)d_in[1];
    const float* Wk = (const float*)d_in[2];
    const float* Wv = (const float*)d_in[3];
    const float* We = (const float*)d_in[4];
    const float* Wo = (const float*)d_in[5];
    const float* bo = (const float*)d_in[6];

    const size_t NT = (size_t)8 * Hc * Lc * DHc;     // 4,194,304 elems
    unsigned short* qw  = (unsigned short*)d_ws;
    unsigned short* kw  = qw  + NT;
    unsigned short* vtg = kw  + NT;                  // V^T (B,H,DH,L)
    unsigned short* awb = vtg + NT;                  // attn out bf16 (B,L,D)
    unsigned short* wqb = awb + NT;
    unsigned short* wkb = wqb + 262144;
    unsigned short* wvb = wkb + 262144;
    unsigned short* wob = wvb + 262144;
    unsigned short* wet = wob + 262144;              // 65536 + 4096 pad (panel-16 DMA overread)

    cvt_w_kernel<<<1088, 256, 0, stream>>>(Wq, Wk, Wv, Wo, We,
                                           wqb, wkb, wvb, wob, wet);
    proj_mfma_kernel<<<dim3(4, 64, 3), 256, 0, stream>>>(x, wqb, wkb, wvb,
                                                         qw, kw, vtg,
                                                         0.125f * 1.44269504089f);
    attn_v5_kernel<<<1024, 256, 0, stream>>>(qw, kw, vtg, wet, awb);
    out_mfma_kernel<<<dim3(4, 64), 256, 0, stream>>>(awb, wob, bo, (float*)d_out);
}

// Round 8
// 212.202 us; speedup vs baseline: 1.0467x; 1.0467x over previous
//
#include <hip/hip_runtime.h>

#define Lc 1024
#define Dc 512
#define Hc 8
#define DHc 64

typedef __attribute__((ext_vector_type(8))) short bf16x8;
typedef __attribute__((ext_vector_type(4))) float f32x4;

typedef __attribute__((address_space(1))) const unsigned int guint;
typedef __attribute__((address_space(3))) unsigned int luint;

__device__ __forceinline__ void gload_lds16(const void* g, void* l) {
    __builtin_amdgcn_global_load_lds((guint*)g, (luint*)l, 16, 0, 0);
}

__device__ __forceinline__ unsigned short f2bf(float f) {
    unsigned u = __float_as_uint(f);
    u += 0x7fffu + ((u >> 16) & 1u);          // round-to-nearest-even
    return (unsigned short)(u >> 16);
}
__device__ __forceinline__ unsigned short f2bft(float f) {   // truncate
    return (unsigned short)(__float_as_uint(f) >> 16);
}
__device__ __forceinline__ unsigned pk2(float a, float b) {
    return (unsigned)f2bf(a) | ((unsigned)f2bf(b) << 16);
}
__device__ __forceinline__ float bf2f(unsigned short s) { return __uint_as_float(((unsigned)s) << 16); }

// ---------------------------------------------------------------------------
// fp32 -> bf16 cast of x, Wq, Wk, Wv, Wo, We
// ---------------------------------------------------------------------------
__global__ void cvt_all_kernel(
    const float* __restrict__ x,  const float* __restrict__ Wq,
    const float* __restrict__ Wk, const float* __restrict__ Wv,
    const float* __restrict__ Wo, const float* __restrict__ We,
    unsigned short* __restrict__ xb,  unsigned short* __restrict__ wqb,
    unsigned short* __restrict__ wkb, unsigned short* __restrict__ wvb,
    unsigned short* __restrict__ wob, unsigned short* __restrict__ wet)
{
    int bid = blockIdx.x;
    const float* src; unsigned short* dst; size_t base;
    if      (bid < 4096) { src = x;  dst = xb;  base = (size_t)bid * 1024; }
    else if (bid < 4352) { src = Wq; dst = wqb; base = (size_t)(bid-4096) * 1024; }
    else if (bid < 4608) { src = Wk; dst = wkb; base = (size_t)(bid-4352) * 1024; }
    else if (bid < 4864) { src = Wv; dst = wvb; base = (size_t)(bid-4608) * 1024; }
    else if (bid < 5120) { src = Wo; dst = wob; base = (size_t)(bid-4864) * 1024; }
    else                 { src = We; dst = wet; base = (size_t)(bid-5120) * 1024; }
    size_t i = base + (size_t)threadIdx.x * 4;
    float4 a = *(const float4*)&src[i];
    *(uint2*)&dst[i] = make_uint2(pk2(a.x, a.y), pk2(a.z, a.w));
}

// ---------------------------------------------------------------------------
// QKV projection, bf16 MFMA, BK=64, full-DMA staging (R6-proven).
// z<2 (q,k): operand-swapped MFMA -> f32x4 spans 4 consecutive dh -> uint2
//            stores to (B,H,L,DH).  qscale = 0.125*log2(e) folded into Q.
// z==2 (v):  normal orientation + LDS-transpose epilogue -> V^T (B,H,DH,L).
// ---------------------------------------------------------------------------
__global__ __launch_bounds__(256, 3) void proj_mfma_kernel(
    const unsigned short* __restrict__ xb,
    const unsigned short* __restrict__ wq, const unsigned short* __restrict__ wk,
    const unsigned short* __restrict__ wv,
    unsigned short* __restrict__ qo, unsigned short* __restrict__ ko,
    unsigned short* __restrict__ vtg, float qscale)
{
    const unsigned short* W;
    if (blockIdx.z == 0)      W = wq;
    else if (blockIdx.z == 1) W = wk;
    else                      W = wv;

    __shared__ unsigned short smem[128 * 136];      // As(8192) Bs(8192) / Ts(17408)
    unsigned short* As = smem;
    unsigned short* Bs = smem + 8192;

    const int t = threadIdx.x;
    const int lane = t & 63, w = t >> 6;
    const int lq = lane >> 4, ln = lane & 15;
    const int m0 = blockIdx.y * 128, n0 = blockIdx.x * 128;
    const int wm = (w & 1) * 64, wn = (w >> 1) * 64;
    const int srow = t >> 3;                        // 0..31
    const int lsg  = ((t & 7) ^ ((t >> 3) & 7)) * 8;  // swizzled source seg*8
    const int key  = ln & 7;

    f32x4 acc[4][4];
    #pragma unroll
    for (int i = 0; i < 4; i++)
        #pragma unroll
        for (int j = 0; j < 4; j++) acc[i][j] = (f32x4){0.f,0.f,0.f,0.f};

    for (int c0 = 0; c0 < 512; c0 += 64) {
        __syncthreads();
        #pragma unroll
        for (int g = 0; g < 4; g++) {
            gload_lds16(&xb[(size_t)(m0 + 32*g + srow) * 512 + c0 + lsg], &As[(32*g + srow)*64 + (t&7)*8]);
            gload_lds16(&W [(size_t)(n0 + 32*g + srow) * 512 + c0 + lsg], &Bs[(32*g + srow)*64 + (t&7)*8]);
        }
        __syncthreads();

        #pragma unroll
        for (int kk = 0; kk < 2; kk++) {
            bf16x8 af[4], bf[4];
            #pragma unroll
            for (int i = 0; i < 4; i++)
                af[i] = *(bf16x8*)&As[(wm + 16*i + ln)*64 + ((kk*4 + lq) ^ key)*8];
            #pragma unroll
            for (int j = 0; j < 4; j++)
                bf[j] = *(bf16x8*)&Bs[(wn + 16*j + ln)*64 + ((kk*4 + lq) ^ key)*8];
            if (blockIdx.z < 2) {
                #pragma unroll
                for (int i = 0; i < 4; i++)
                    #pragma unroll
                    for (int j = 0; j < 4; j++)
                        acc[i][j] = __builtin_amdgcn_mfma_f32_16x16x32_bf16(bf[j], af[i], acc[i][j], 0, 0, 0);
            } else {
                #pragma unroll
                for (int i = 0; i < 4; i++)
                    #pragma unroll
                    for (int j = 0; j < 4; j++)
                        acc[i][j] = __builtin_amdgcn_mfma_f32_16x16x32_bf16(af[i], bf[j], acc[i][j], 0, 0, 0);
            }
        }
    }

    if (blockIdx.z < 2) {
        // swapped: D row-dim = n (W rows), col-dim = m (x rows)
        unsigned short* out = (blockIdx.z == 0) ? qo : ko;
        const float osc = (blockIdx.z == 0) ? qscale : 1.0f;
        #pragma unroll
        for (int i = 0; i < 4; i++) {
            int m = m0 + wm + 16*i + ln;
            int b = m >> 10, l = m & 1023;
            #pragma unroll
            for (int j = 0; j < 4; j++) {
                int nb = n0 + wn + 16*j + 4*lq;     // 4-aligned dh base
                int h = nb >> 6, dh = nb & 63;
                *(uint2*)&out[((size_t)((b*Hc + h)*Lc + l))*DHc + dh] =
                    make_uint2(pk2(acc[i][j][0]*osc, acc[i][j][1]*osc),
                               pk2(acc[i][j][2]*osc, acc[i][j][3]*osc));
            }
        }
    } else {
        // V: transpose through LDS, write V^T (B,H,DH,L)
        __syncthreads();
        unsigned short* Ts = smem;      // [n_local][m_local] stride 136
        #pragma unroll
        for (int i = 0; i < 4; i++) {
            int mlb = wm + 16*i + 4*lq;
            #pragma unroll
            for (int j = 0; j < 4; j++) {
                int nl = wn + 16*j + ln;
                *(uint2*)&Ts[nl*136 + mlb] = make_uint2(pk2(acc[i][j][0], acc[i][j][1]),
                                                        pk2(acc[i][j][2], acc[i][j][3]));
            }
        }
        __syncthreads();
        const int b = m0 >> 10, l0m = m0 & 1023;
        const int nl = t >> 1, seg = (t & 1) * 64;
        const int ng = n0 + nl, h = ng >> 6, dh = ng & 63;
        unsigned short* dst = vtg + (((size_t)(b*Hc + h))*DHc + dh)*Lc + l0m + seg;
        #pragma unroll
        for (int u = 0; u < 8; u++)
            *(uint4*)&dst[8*u] = *(uint4*)&Ts[nl*136 + seg + 8*u];
    }
}

// ---------------------------------------------------------------------------
// Output GEMM, bf16 MFMA, 64x64 tiles (1024 blocks = 4/CU; the 128x128
// version ran 1 block/CU and was latency-bound). BK=64, swizzled DMA.
// out = awb @ Wo^T + bo (fp32 out).
// ---------------------------------------------------------------------------
__global__ __launch_bounds__(256, 4) void out_mfma_kernel(
    const unsigned short* __restrict__ A, const unsigned short* __restrict__ W,
    const float* __restrict__ bias, float* __restrict__ out)
{
    __shared__ unsigned short As[64 * 64];
    __shared__ unsigned short Bs[64 * 64];

    const int t = threadIdx.x;
    const int lane = t & 63, w = t >> 6;
    const int lq = lane >> 4, ln = lane & 15;
    const int m0 = blockIdx.y * 64, n0 = blockIdx.x * 64;
    const int wm = (w & 1) * 32, wn = (w >> 1) * 32;
    const int srow = t >> 3;                        // 0..31
    const int lsg  = ((t & 7) ^ ((t >> 3) & 7)) * 8;
    const int key  = ln & 7;

    f32x4 acc[2][2];
    #pragma unroll
    for (int i = 0; i < 2; i++)
        #pragma unroll
        for (int j = 0; j < 2; j++) acc[i][j] = (f32x4){0.f,0.f,0.f,0.f};

    for (int c0 = 0; c0 < 512; c0 += 64) {
        __syncthreads();
        #pragma unroll
        for (int g = 0; g < 2; g++) {
            gload_lds16(&A[(size_t)(m0 + 32*g + srow) * 512 + c0 + lsg], &As[(32*g + srow)*64 + (t&7)*8]);
            gload_lds16(&W[(size_t)(n0 + 32*g + srow) * 512 + c0 + lsg], &Bs[(32*g + srow)*64 + (t&7)*8]);
        }
        __syncthreads();

        #pragma unroll
        for (int kk = 0; kk < 2; kk++) {
            bf16x8 af[2], bf[2];
            #pragma unroll
            for (int i = 0; i < 2; i++)
                af[i] = *(bf16x8*)&As[(wm + 16*i + ln)*64 + ((kk*4 + lq) ^ key)*8];
            #pragma unroll
            for (int j = 0; j < 2; j++)
                bf[j] = *(bf16x8*)&Bs[(wn + 16*j + ln)*64 + ((kk*4 + lq) ^ key)*8];
            #pragma unroll
            for (int i = 0; i < 2; i++)
                #pragma unroll
                for (int j = 0; j < 2; j++)
                    acc[i][j] = __builtin_amdgcn_mfma_f32_16x16x32_bf16(af[i], bf[j], acc[i][j], 0, 0, 0);
        }
    }

    float bb[2];
    #pragma unroll
    for (int j = 0; j < 2; j++) bb[j] = bias[n0 + wn + 16*j + ln];

    #pragma unroll
    for (int i = 0; i < 2; i++) {
        #pragma unroll
        for (int r = 0; r < 4; r++) {
            int m = m0 + wm + 16*i + 4*lq + r;
            #pragma unroll
            for (int j = 0; j < 2; j++) {
                int n = n0 + wn + 16*j + ln;
                out[(size_t)m * Dc + n] = acc[i][j][r] + bb[j];
            }
        }
    }
}

// ---------------------------------------------------------------------------
// attn v5 (unchanged from R7; 73.7 us proven):
//  rolling QE band + MFMA row-sums + exp2 folding + trunc-P + ring QE addr.
// ---------------------------------------------------------------------------
__global__ __launch_bounds__(256, 3) void attn_v5_kernel(
    const unsigned short* __restrict__ q, const unsigned short* __restrict__ k,
    const unsigned short* __restrict__ vtg, const unsigned short* __restrict__ wet,
    unsigned short* __restrict__ attn)
{
    __shared__ unsigned short ksp [2 * 64 * 32];    // K planes [kk][s][32]
    __shared__ unsigned short vtp [2 * 64 * 32];    // V^T planes [kk][dd][32]
    __shared__ unsigned short wesp[2 * 64 * 32];    // We new-panel planes
    __shared__ unsigned short ps  [2 * 64 * 32];    // P planes (intra-wave)
    __shared__ unsigned short qes [128 * 70];       // QE ring [e&127][l]

    const int t    = threadIdx.x;
    const int lane = t & 63, w = t >> 6;
    const int lq   = lane >> 4, ln = lane & 15;

    const int n   = blockIdx.x;
    const int xcd = n & 7, idx = n >> 3;
    const int bh  = xcd * 8 + (idx >> 4);
    const int l0  = (idx & 15) * 64;

    const unsigned short* qb  = q   + (size_t)bh * (Lc * DHc);
    const unsigned short* kb  = k   + (size_t)bh * (Lc * DHc);
    const unsigned short* vtb = vtg + (size_t)bh * (DHc * Lc);

    const int trow = t >> 2;
    const int sseg = ((t & 3) ^ ((t >> 4) & 3)) * 8;
    const int swz  = (ln >> 2) & 3;

    const bf16x8 onesf = {(short)0x3F80,(short)0x3F80,(short)0x3F80,(short)0x3F80,
                          (short)0x3F80,(short)0x3F80,(short)0x3F80,(short)0x3F80};

    bf16x8 qa[2];
    #pragma unroll
    for (int kk = 0; kk < 2; kk++)
        qa[kk] = *(const bf16x8*)&qb[(size_t)(l0 + 16*w + ln)*64 + kk*32 + lq*8];

    const int pb0 = 15 - (l0 >> 6);
    gload_lds16(&wet[(size_t)(64*pb0 + trow)*64 +      sseg], &wesp[t*8]);
    gload_lds16(&wet[(size_t)(64*pb0 + trow)*64 + 32 + sseg], &wesp[2048 + t*8]);
    __syncthreads();
    {
        f32x4 qec[4];
        #pragma unroll
        for (int c = 0; c < 4; c++) qec[c] = (f32x4){0.f,0.f,0.f,0.f};
        #pragma unroll
        for (int kk = 0; kk < 2; kk++)
            #pragma unroll
            for (int c = 0; c < 4; c++) {
                bf16x8 bf = *(bf16x8*)&wesp[kk*2048 + (16*c + ln)*32 + (lq ^ swz)*8];
                qec[c] = __builtin_amdgcn_mfma_f32_16x16x32_bf16(qa[kk], bf, qec[c], 0, 0, 0);
            }
        const int cb = (pb0 & 1) * 64;
        #pragma unroll
        for (int c = 0; c < 4; c++)
            *(uint2*)&qes[(cb + 16*c + ln)*70 + 16*w + 4*lq] =
                make_uint2(pk2(qec[c][0], qec[c][1]), pk2(qec[c][2], qec[c][3]));
    }

    f32x4 Lacc = (f32x4){0.f, 0.f, 0.f, 0.f};
    f32x4 Ov[4];
    #pragma unroll
    for (int c = 0; c < 4; c++) Ov[c] = (f32x4){0.f, 0.f, 0.f, 0.f};

    int pbOld = pb0 - 1;

    for (int s0 = 0; s0 < Lc; s0 += 64) {
        const int c0  = l0 - s0;
        const int ac0 = c0 < 0 ? -c0 : c0;
        const int pb  = (960 - ac0) >> 6;
        const int newp = (pb > pbOld) ? pb + 1 : pb;
        pbOld = pb;
        const int cb = (newp & 1) * 64;

        __syncthreads();
        gload_lds16(&kb [(size_t)(s0 + trow)*64 +      sseg], &ksp [t*8]);
        gload_lds16(&kb [(size_t)(s0 + trow)*64 + 32 + sseg], &ksp [2048 + t*8]);
        gload_lds16(&vtb[(size_t)trow*1024 + s0 +      sseg], &vtp [t*8]);
        gload_lds16(&vtb[(size_t)trow*1024 + s0 + 32 + sseg], &vtp [2048 + t*8]);
        gload_lds16(&wet[(size_t)(64*newp + trow)*64 +      sseg], &wesp[t*8]);
        gload_lds16(&wet[(size_t)(64*newp + trow)*64 + 32 + sseg], &wesp[2048 + t*8]);
        __syncthreads();

        {
            f32x4 qec[4];
            #pragma unroll
            for (int c = 0; c < 4; c++) qec[c] = (f32x4){0.f,0.f,0.f,0.f};
            #pragma unroll
            for (int kk = 0; kk < 2; kk++)
                #pragma unroll
                for (int c = 0; c < 4; c++) {
                    bf16x8 bf = *(bf16x8*)&wesp[kk*2048 + (16*c + ln)*32 + (lq ^ swz)*8];
                    qec[c] = __builtin_amdgcn_mfma_f32_16x16x32_bf16(qa[kk], bf, qec[c], 0, 0, 0);
                }
            #pragma unroll
            for (int c = 0; c < 4; c++)
                *(uint2*)&qes[(cb + 16*c + ln)*70 + 16*w + 4*lq] =
                    make_uint2(pk2(qec[c][0], qec[c][1]), pk2(qec[c][2], qec[c][3]));
        }

        f32x4 sc[4];
        #pragma unroll
        for (int c = 0; c < 4; c++) sc[c] = (f32x4){0.f,0.f,0.f,0.f};
        #pragma unroll
        for (int kk = 0; kk < 2; kk++)
            #pragma unroll
            for (int c = 0; c < 4; c++) {
                bf16x8 bfk = *(bf16x8*)&ksp[kk*2048 + (16*c + ln)*32 + (lq ^ swz)*8];
                sc[c] = __builtin_amdgcn_mfma_f32_16x16x32_bf16(qa[kk], bfk, sc[c], 0, 0, 0);
            }

        float p[4][4];
        #pragma unroll
        for (int r = 0; r < 4; r++) {
            const int lr = 16*w + 4*lq + r;
            const int dbase = c0 + lr - ln;
            #pragma unroll
            for (int c = 0; c < 4; c++) {
                int d  = dbase - 16*c;
                int ad = d < 0 ? -d : d;
                int m  = 1023 - ad;
                float bias = bf2f(qes[(m & 127)*70 + lr]);
                p[r][c] = __builtin_amdgcn_exp2f(sc[c][r] + bias);
            }
        }

        #pragma unroll
        for (int r = 0; r < 4; r++) {
            const int lr = 16*w + 4*lq + r;
            #pragma unroll
            for (int c = 0; c < 4; c++) {
                int seg = (((c & 1)*2 + (ln >> 3)) ^ lq);
                ps[(c >> 1)*2048 + lr*32 + seg*8 + (ln & 7)] = f2bft(p[r][c]);
            }
        }

        #pragma unroll
        for (int kk = 0; kk < 2; kk++) {
            bf16x8 pa = *(bf16x8*)&ps[kk*2048 + (16*w + ln)*32 + (lq ^ swz)*8];
            Lacc = __builtin_amdgcn_mfma_f32_16x16x32_bf16(pa, onesf, Lacc, 0, 0, 0);
            #pragma unroll
            for (int c = 0; c < 4; c++) {
                bf16x8 vf = *(bf16x8*)&vtp[kk*2048 + (16*c + ln)*32 + (lq ^ swz)*8];
                Ov[c] = __builtin_amdgcn_mfma_f32_16x16x32_bf16(pa, vf, Ov[c], 0, 0, 0);
            }
        }
    }

    const int b = bh >> 3, h = bh & 7;
    #pragma unroll
    for (int r = 0; r < 4; r++) {
        float inv = 1.f / Lacc[r];
        int l = l0 + 16*w + 4*lq + r;
        #pragma unroll
        for (int c = 0; c < 4; c++)
            attn[((size_t)(b*Lc + l))*Dc + h*DHc + 16*c + ln] = f2bf(Ov[c][r] * inv);
    }
}

extern "C" void kernel_launch(void* const* d_in, const int* in_sizes, int n_in,
                              void* d_out, int out_size, void* d_ws, size_t ws_size,
                              hipStream_t stream)
{
    (void)in_sizes; (void)n_in; (void)out_size; (void)ws_size;
    const float* x  = (const float*)d_in[0];
    const float* Wq = (const float*)d_in[1];
    const float* Wk = (const float*)d_in[2];
    const float* Wv = (const float*)d_in[3];
    const float* We = (const float*)d_in[4];
    const float* Wo = (const float*)d_in[5];
    const float* bo = (const float*)d_in[6];

    const size_t NT = (size_t)8 * Hc * Lc * DHc;     // 4,194,304 elems
    unsigned short* qw  = (unsigned short*)d_ws;
    unsigned short* kw  = qw  + NT;
    unsigned short* vtg = kw  + NT;                  // V^T (B,H,DH,L)
    unsigned short* xbf = vtg + NT;
    unsigned short* awb = xbf + NT;                  // attn out bf16 (B,L,D)
    unsigned short* wqb = awb + NT;
    unsigned short* wkb = wqb + 262144;
    unsigned short* wvb = wkb + 262144;
    unsigned short* wob = wvb + 262144;
    unsigned short* wet = wob + 262144;              // 65536 + 4096 pad (panel-16 DMA overread)

    cvt_all_kernel<<<5184, 256, 0, stream>>>(x, Wq, Wk, Wv, Wo, We,
                                             xbf, wqb, wkb, wvb, wob, wet);
    proj_mfma_kernel<<<dim3(4, 64, 3), 256, 0, stream>>>(xbf, wqb, wkb, wvb,
                                                         qw, kw, vtg,
                                                         0.125f * 1.44269504089f);
    attn_v5_kernel<<<1024, 256, 0, stream>>>(qw, kw, vtg, wet, awb);
    out_mfma_kernel<<<dim3(8, 128), 256, 0, stream>>>(awb, wob, bo, (float*)d_out);
}

// Round 9
// 180.460 us; speedup vs baseline: 1.2308x; 1.1759x over previous
//
#include <hip/hip_runtime.h>

#define Lc 1024
#define Dc 512
#define Hc 8
#define DHc 64

typedef __attribute__((ext_vector_type(8))) short bf16x8;
typedef __attribute__((ext_vector_type(4))) float f32x4;

typedef __attribute__((address_space(1))) const unsigned int guint;
typedef __attribute__((address_space(3))) unsigned int luint;

__device__ __forceinline__ void gload_lds16(const void* g, void* l) {
    __builtin_amdgcn_global_load_lds((guint*)g, (luint*)l, 16, 0, 0);
}

__device__ __forceinline__ unsigned short f2bf(float f) {
    unsigned u = __float_as_uint(f);
    u += 0x7fffu + ((u >> 16) & 1u);          // round-to-nearest-even
    return (unsigned short)(u >> 16);
}
__device__ __forceinline__ unsigned short f2bft(float f) {   // truncate
    return (unsigned short)(__float_as_uint(f) >> 16);
}
__device__ __forceinline__ unsigned pk2(float a, float b) {
    return (unsigned)f2bf(a) | ((unsigned)f2bf(b) << 16);
}
__device__ __forceinline__ float bf2f(unsigned short s) { return __uint_as_float(((unsigned)s) << 16); }

// ---------------------------------------------------------------------------
// fp32 -> bf16 cast of x, Wq, Wk, Wv, Wo, We
// ---------------------------------------------------------------------------
__global__ void cvt_all_kernel(
    const float* __restrict__ x,  const float* __restrict__ Wq,
    const float* __restrict__ Wk, const float* __restrict__ Wv,
    const float* __restrict__ Wo, const float* __restrict__ We,
    unsigned short* __restrict__ xb,  unsigned short* __restrict__ wqb,
    unsigned short* __restrict__ wkb, unsigned short* __restrict__ wvb,
    unsigned short* __restrict__ wob, unsigned short* __restrict__ wet)
{
    int bid = blockIdx.x;
    const float* src; unsigned short* dst; size_t base;
    if      (bid < 4096) { src = x;  dst = xb;  base = (size_t)bid * 1024; }
    else if (bid < 4352) { src = Wq; dst = wqb; base = (size_t)(bid-4096) * 1024; }
    else if (bid < 4608) { src = Wk; dst = wkb; base = (size_t)(bid-4352) * 1024; }
    else if (bid < 4864) { src = Wv; dst = wvb; base = (size_t)(bid-4608) * 1024; }
    else if (bid < 5120) { src = Wo; dst = wob; base = (size_t)(bid-4864) * 1024; }
    else                 { src = We; dst = wet; base = (size_t)(bid-5120) * 1024; }
    size_t i = base + (size_t)threadIdx.x * 4;
    float4 a = *(const float4*)&src[i];
    *(uint2*)&dst[i] = make_uint2(pk2(a.x, a.y), pk2(a.z, a.w));
}

// ---------------------------------------------------------------------------
// QKV projection, bf16 MFMA, BK=64, full-DMA staging (R6-proven config).
// Normal orientation for all z; q/k epilogue: quad-contiguous scalar stores;
// z==2 (v): LDS-transpose epilogue -> V^T (B,H,DH,L).
// qscale = 0.125*log2(e) folded into Q.
// ---------------------------------------------------------------------------
__global__ __launch_bounds__(256, 3) void proj_mfma_kernel(
    const unsigned short* __restrict__ xb,
    const unsigned short* __restrict__ wq, const unsigned short* __restrict__ wk,
    const unsigned short* __restrict__ wv,
    unsigned short* __restrict__ qo, unsigned short* __restrict__ ko,
    unsigned short* __restrict__ vtg, float qscale)
{
    const unsigned short* W;
    if (blockIdx.z == 0)      W = wq;
    else if (blockIdx.z == 1) W = wk;
    else                      W = wv;

    __shared__ unsigned short smem[128 * 136];      // As(8192) Bs(8192) / Ts(17408)
    unsigned short* As = smem;
    unsigned short* Bs = smem + 8192;

    const int t = threadIdx.x;
    const int lane = t & 63, w = t >> 6;
    const int lq = lane >> 4, ln = lane & 15;
    const int m0 = blockIdx.y * 128, n0 = blockIdx.x * 128;
    const int wm = (w & 1) * 64, wn = (w >> 1) * 64;
    const int srow = t >> 3;                        // 0..31
    const int lsg  = ((t & 7) ^ ((t >> 3) & 7)) * 8;  // swizzled source seg*8
    const int key  = ln & 7;

    f32x4 acc[4][4];
    #pragma unroll
    for (int i = 0; i < 4; i++)
        #pragma unroll
        for (int j = 0; j < 4; j++) acc[i][j] = (f32x4){0.f,0.f,0.f,0.f};

    for (int c0 = 0; c0 < 512; c0 += 64) {
        __syncthreads();
        #pragma unroll
        for (int g = 0; g < 4; g++) {
            gload_lds16(&xb[(size_t)(m0 + 32*g + srow) * 512 + c0 + lsg], &As[(32*g + srow)*64 + (t&7)*8]);
            gload_lds16(&W [(size_t)(n0 + 32*g + srow) * 512 + c0 + lsg], &Bs[(32*g + srow)*64 + (t&7)*8]);
        }
        __syncthreads();

        #pragma unroll
        for (int kk = 0; kk < 2; kk++) {
            bf16x8 af[4], bf[4];
            #pragma unroll
            for (int i = 0; i < 4; i++)
                af[i] = *(bf16x8*)&As[(wm + 16*i + ln)*64 + ((kk*4 + lq) ^ key)*8];
            #pragma unroll
            for (int j = 0; j < 4; j++)
                bf[j] = *(bf16x8*)&Bs[(wn + 16*j + ln)*64 + ((kk*4 + lq) ^ key)*8];
            #pragma unroll
            for (int i = 0; i < 4; i++)
                #pragma unroll
                for (int j = 0; j < 4; j++)
                    acc[i][j] = __builtin_amdgcn_mfma_f32_16x16x32_bf16(af[i], bf[j], acc[i][j], 0, 0, 0);
        }
    }

    if (blockIdx.z < 2) {
        unsigned short* out = (blockIdx.z == 0) ? qo : ko;
        const float osc = (blockIdx.z == 0) ? qscale : 1.0f;
        #pragma unroll
        for (int i = 0; i < 4; i++) {
            #pragma unroll
            for (int r = 0; r < 4; r++) {
                int m = m0 + wm + 16*i + 4*lq + r;
                int b = m >> 10, l = m & 1023;
                #pragma unroll
                for (int j = 0; j < 4; j++) {
                    int n = n0 + wn + 16*j + ln;
                    int h = n >> 6, dh = n & 63;
                    out[((size_t)((b*Hc + h)*Lc + l))*DHc + dh] = f2bf(acc[i][j][r] * osc);
                }
            }
        }
    } else {
        // V: transpose through LDS, write V^T (B,H,DH,L)
        __syncthreads();
        unsigned short* Ts = smem;      // [n_local][m_local] stride 136
        #pragma unroll
        for (int i = 0; i < 4; i++) {
            int mlb = wm + 16*i + 4*lq;
            #pragma unroll
            for (int j = 0; j < 4; j++) {
                int nl = wn + 16*j + ln;
                *(uint2*)&Ts[nl*136 + mlb] = make_uint2(pk2(acc[i][j][0], acc[i][j][1]),
                                                        pk2(acc[i][j][2], acc[i][j][3]));
            }
        }
        __syncthreads();
        const int b = m0 >> 10, l0m = m0 & 1023;
        const int nl = t >> 1, seg = (t & 1) * 64;
        const int ng = n0 + nl, h = ng >> 6, dh = ng & 63;
        unsigned short* dst = vtg + (((size_t)(b*Hc + h))*DHc + dh)*Lc + l0m + seg;
        #pragma unroll
        for (int u = 0; u < 8; u++)
            *(uint4*)&dst[8*u] = *(uint4*)&Ts[nl*136 + seg + 8*u];
    }
}

// ---------------------------------------------------------------------------
// Output GEMM, bf16 MFMA, 64x64 tiles (1024 blocks = 4/CU). BK=64, swizzled
// DMA. out = awb @ Wo^T + bo (fp32 out).
// ---------------------------------------------------------------------------
__global__ __launch_bounds__(256, 4) void out_mfma_kernel(
    const unsigned short* __restrict__ A, const unsigned short* __restrict__ W,
    const float* __restrict__ bias, float* __restrict__ out)
{
    __shared__ unsigned short As[64 * 64];
    __shared__ unsigned short Bs[64 * 64];

    const int t = threadIdx.x;
    const int lane = t & 63, w = t >> 6;
    const int lq = lane >> 4, ln = lane & 15;
    const int m0 = blockIdx.y * 64, n0 = blockIdx.x * 64;
    const int wm = (w & 1) * 32, wn = (w >> 1) * 32;
    const int srow = t >> 3;                        // 0..31
    const int lsg  = ((t & 7) ^ ((t >> 3) & 7)) * 8;
    const int key  = ln & 7;

    f32x4 acc[2][2];
    #pragma unroll
    for (int i = 0; i < 2; i++)
        #pragma unroll
        for (int j = 0; j < 2; j++) acc[i][j] = (f32x4){0.f,0.f,0.f,0.f};

    for (int c0 = 0; c0 < 512; c0 += 64) {
        __syncthreads();
        #pragma unroll
        for (int g = 0; g < 2; g++) {
            gload_lds16(&A[(size_t)(m0 + 32*g + srow) * 512 + c0 + lsg], &As[(32*g + srow)*64 + (t&7)*8]);
            gload_lds16(&W[(size_t)(n0 + 32*g + srow) * 512 + c0 + lsg], &Bs[(32*g + srow)*64 + (t&7)*8]);
        }
        __syncthreads();

        #pragma unroll
        for (int kk = 0; kk < 2; kk++) {
            bf16x8 af[2], bf[2];
            #pragma unroll
            for (int i = 0; i < 2; i++)
                af[i] = *(bf16x8*)&As[(wm + 16*i + ln)*64 + ((kk*4 + lq) ^ key)*8];
            #pragma unroll
            for (int j = 0; j < 2; j++)
                bf[j] = *(bf16x8*)&Bs[(wn + 16*j + ln)*64 + ((kk*4 + lq) ^ key)*8];
            #pragma unroll
            for (int i = 0; i < 2; i++)
                #pragma unroll
                for (int j = 0; j < 2; j++)
                    acc[i][j] = __builtin_amdgcn_mfma_f32_16x16x32_bf16(af[i], bf[j], acc[i][j], 0, 0, 0);
        }
    }

    float bb[2];
    #pragma unroll
    for (int j = 0; j < 2; j++) bb[j] = bias[n0 + wn + 16*j + ln];

    #pragma unroll
    for (int i = 0; i < 2; i++) {
        #pragma unroll
        for (int r = 0; r < 4; r++) {
            int m = m0 + wm + 16*i + 4*lq + r;
            #pragma unroll
            for (int j = 0; j < 2; j++) {
                int n = n0 + wn + 16*j + ln;
                out[(size_t)m * Dc + n] = acc[i][j][r] + bb[j];
            }
        }
    }
}

// ---------------------------------------------------------------------------
// attn v5 (unchanged; 73.7 us proven):
//  rolling QE band + MFMA row-sums + exp2 folding + trunc-P + ring QE addr.
// ---------------------------------------------------------------------------
__global__ __launch_bounds__(256, 3) void attn_v5_kernel(
    const unsigned short* __restrict__ q, const unsigned short* __restrict__ k,
    const unsigned short* __restrict__ vtg, const unsigned short* __restrict__ wet,
    unsigned short* __restrict__ attn)
{
    __shared__ unsigned short ksp [2 * 64 * 32];    // K planes [kk][s][32]
    __shared__ unsigned short vtp [2 * 64 * 32];    // V^T planes [kk][dd][32]
    __shared__ unsigned short wesp[2 * 64 * 32];    // We new-panel planes
    __shared__ unsigned short ps  [2 * 64 * 32];    // P planes (intra-wave)
    __shared__ unsigned short qes [128 * 70];       // QE ring [e&127][l]

    const int t    = threadIdx.x;
    const int lane = t & 63, w = t >> 6;
    const int lq   = lane >> 4, ln = lane & 15;

    const int n   = blockIdx.x;
    const int xcd = n & 7, idx = n >> 3;
    const int bh  = xcd * 8 + (idx >> 4);
    const int l0  = (idx & 15) * 64;

    const unsigned short* qb  = q   + (size_t)bh * (Lc * DHc);
    const unsigned short* kb  = k   + (size_t)bh * (Lc * DHc);
    const unsigned short* vtb = vtg + (size_t)bh * (DHc * Lc);

    const int trow = t >> 2;
    const int sseg = ((t & 3) ^ ((t >> 4) & 3)) * 8;
    const int swz  = (ln >> 2) & 3;

    const bf16x8 onesf = {(short)0x3F80,(short)0x3F80,(short)0x3F80,(short)0x3F80,
                          (short)0x3F80,(short)0x3F80,(short)0x3F80,(short)0x3F80};

    bf16x8 qa[2];
    #pragma unroll
    for (int kk = 0; kk < 2; kk++)
        qa[kk] = *(const bf16x8*)&qb[(size_t)(l0 + 16*w + ln)*64 + kk*32 + lq*8];

    const int pb0 = 15 - (l0 >> 6);
    gload_lds16(&wet[(size_t)(64*pb0 + trow)*64 +      sseg], &wesp[t*8]);
    gload_lds16(&wet[(size_t)(64*pb0 + trow)*64 + 32 + sseg], &wesp[2048 + t*8]);
    __syncthreads();
    {
        f32x4 qec[4];
        #pragma unroll
        for (int c = 0; c < 4; c++) qec[c] = (f32x4){0.f,0.f,0.f,0.f};
        #pragma unroll
        for (int kk = 0; kk < 2; kk++)
            #pragma unroll
            for (int c = 0; c < 4; c++) {
                bf16x8 bf = *(bf16x8*)&wesp[kk*2048 + (16*c + ln)*32 + (lq ^ swz)*8];
                qec[c] = __builtin_amdgcn_mfma_f32_16x16x32_bf16(qa[kk], bf, qec[c], 0, 0, 0);
            }
        const int cb = (pb0 & 1) * 64;
        #pragma unroll
        for (int c = 0; c < 4; c++)
            *(uint2*)&qes[(cb + 16*c + ln)*70 + 16*w + 4*lq] =
                make_uint2(pk2(qec[c][0], qec[c][1]), pk2(qec[c][2], qec[c][3]));
    }

    f32x4 Lacc = (f32x4){0.f, 0.f, 0.f, 0.f};
    f32x4 Ov[4];
    #pragma unroll
    for (int c = 0; c < 4; c++) Ov[c] = (f32x4){0.f, 0.f, 0.f, 0.f};

    int pbOld = pb0 - 1;

    for (int s0 = 0; s0 < Lc; s0 += 64) {
        const int c0  = l0 - s0;
        const int ac0 = c0 < 0 ? -c0 : c0;
        const int pb  = (960 - ac0) >> 6;
        const int newp = (pb > pbOld) ? pb + 1 : pb;
        pbOld = pb;
        const int cb = (newp & 1) * 64;

        __syncthreads();
        gload_lds16(&kb [(size_t)(s0 + trow)*64 +      sseg], &ksp [t*8]);
        gload_lds16(&kb [(size_t)(s0 + trow)*64 + 32 + sseg], &ksp [2048 + t*8]);
        gload_lds16(&vtb[(size_t)trow*1024 + s0 +      sseg], &vtp [t*8]);
        gload_lds16(&vtb[(size_t)trow*1024 + s0 + 32 + sseg], &vtp [2048 + t*8]);
        gload_lds16(&wet[(size_t)(64*newp + trow)*64 +      sseg], &wesp[t*8]);
        gload_lds16(&wet[(size_t)(64*newp + trow)*64 + 32 + sseg], &wesp[2048 + t*8]);
        __syncthreads();

        {
            f32x4 qec[4];
            #pragma unroll
            for (int c = 0; c < 4; c++) qec[c] = (f32x4){0.f,0.f,0.f,0.f};
            #pragma unroll
            for (int kk = 0; kk < 2; kk++)
                #pragma unroll
                for (int c = 0; c < 4; c++) {
                    bf16x8 bf = *(bf16x8*)&wesp[kk*2048 + (16*c + ln)*32 + (lq ^ swz)*8];
                    qec[c] = __builtin_amdgcn_mfma_f32_16x16x32_bf16(qa[kk], bf, qec[c], 0, 0, 0);
                }
            #pragma unroll
            for (int c = 0; c < 4; c++)
                *(uint2*)&qes[(cb + 16*c + ln)*70 + 16*w + 4*lq] =
                    make_uint2(pk2(qec[c][0], qec[c][1]), pk2(qec[c][2], qec[c][3]));
        }

        f32x4 sc[4];
        #pragma unroll
        for (int c = 0; c < 4; c++) sc[c] = (f32x4){0.f,0.f,0.f,0.f};
        #pragma unroll
        for (int kk = 0; kk < 2; kk++)
            #pragma unroll
            for (int c = 0; c < 4; c++) {
                bf16x8 bfk = *(bf16x8*)&ksp[kk*2048 + (16*c + ln)*32 + (lq ^ swz)*8];
                sc[c] = __builtin_amdgcn_mfma_f32_16x16x32_bf16(qa[kk], bfk, sc[c], 0, 0, 0);
            }

        float p[4][4];
        #pragma unroll
        for (int r = 0; r < 4; r++) {
            const int lr = 16*w + 4*lq + r;
            const int dbase = c0 + lr - ln;
            #pragma unroll
            for (int c = 0; c < 4; c++) {
                int d  = dbase - 16*c;
                int ad = d < 0 ? -d : d;
                int m  = 1023 - ad;
                float bias = bf2f(qes[(m & 127)*70 + lr]);
                p[r][c] = __builtin_amdgcn_exp2f(sc[c][r] + bias);
            }
        }

        #pragma unroll
        for (int r = 0; r < 4; r++) {
            const int lr = 16*w + 4*lq + r;
            #pragma unroll
            for (int c = 0; c < 4; c++) {
                int seg = (((c & 1)*2 + (ln >> 3)) ^ lq);
                ps[(c >> 1)*2048 + lr*32 + seg*8 + (ln & 7)] = f2bft(p[r][c]);
            }
        }

        #pragma unroll
        for (int kk = 0; kk < 2; kk++) {
            bf16x8 pa = *(bf16x8*)&ps[kk*2048 + (16*w + ln)*32 + (lq ^ swz)*8];
            Lacc = __builtin_amdgcn_mfma_f32_16x16x32_bf16(pa, onesf, Lacc, 0, 0, 0);
            #pragma unroll
            for (int c = 0; c < 4; c++) {
                bf16x8 vf = *(bf16x8*)&vtp[kk*2048 + (16*c + ln)*32 + (lq ^ swz)*8];
                Ov[c] = __builtin_amdgcn_mfma_f32_16x16x32_bf16(pa, vf, Ov[c], 0, 0, 0);
            }
        }
    }

    const int b = bh >> 3, h = bh & 7;
    #pragma unroll
    for (int r = 0; r < 4; r++) {
        float inv = 1.f / Lacc[r];
        int l = l0 + 16*w + 4*lq + r;
        #pragma unroll
        for (int c = 0; c < 4; c++)
            attn[((size_t)(b*Lc + l))*Dc + h*DHc + 16*c + ln] = f2bf(Ov[c][r] * inv);
    }
}

extern "C" void kernel_launch(void* const* d_in, const int* in_sizes, int n_in,
                              void* d_out, int out_size, void* d_ws, size_t ws_size,
                              hipStream_t stream)
{
    (void)in_sizes; (void)n_in; (void)out_size; (void)ws_size;
    const float* x  = (const float*)d_in[0];
    const float* Wq = (const float*)d_in[1];
    const float* Wk = (const float*)d_in[2];
    const float* Wv = (const float*)d_in[3];
    const float* We = (const float*)d_in[4];
    const float* Wo = (const float*)d_in[5];
    const float* bo = (const float*)d_in[6];

    const size_t NT = (size_t)8 * Hc * Lc * DHc;     // 4,194,304 elems
    unsigned short* qw  = (unsigned short*)d_ws;
    unsigned short* kw  = qw  + NT;
    unsigned short* vtg = kw  + NT;                  // V^T (B,H,DH,L)
    unsigned short* xbf = vtg + NT;
    unsigned short* awb = xbf + NT;                  // attn out bf16 (B,L,D)
    unsigned short* wqb = awb + NT;
    unsigned short* wkb = wqb + 262144;
    unsigned short* wvb = wkb + 262144;
    unsigned short* wob = wvb + 262144;
    unsigned short* wet = wob + 262144;              // 65536 + 4096 pad (panel-16 DMA overread)

    cvt_all_kernel<<<5184, 256, 0, stream>>>(x, Wq, Wk, Wv, Wo, We,
                                             xbf, wqb, wkb, wvb, wob, wet);
    proj_mfma_kernel<<<dim3(4, 64, 3), 256, 0, stream>>>(xbf, wqb, wkb, wvb,
                                                         qw, kw, vtg,
                                                         0.125f * 1.44269504089f);
    attn_v5_kernel<<<1024, 256, 0, stream>>>(qw, kw, vtg, wet, awb);
    out_mfma_kernel<<<dim3(8, 128), 256, 0, stream>>>(awb, wob, bo, (float*)d_out);
}